// Round 1
// 1029.699 us; speedup vs baseline: 1.1062x; 1.1062x over previous
//
#include <hip/hip_runtime.h>
#include <hip/hip_bf16.h>
#include <cmath>

using bf16 = __hip_bfloat16;
typedef __attribute__((ext_vector_type(8))) short short8;
typedef __attribute__((ext_vector_type(4))) float float4f;

#define THW 25088           // tokens per batch
#define CH_ROWS 25088       // 256 windows * 98 tokens per chunk (1 batch)
#define SCALE_QK 0.17677669529663687f

static __device__ __forceinline__ float4f mfma16(short8 a, short8 b, float4f c) {
  return __builtin_amdgcn_mfma_f32_16x16x32_bf16(a, b, c, 0, 0, 0);
}
static __device__ __forceinline__ short8 load8(const bf16* p) {
  return *reinterpret_cast<const short8*>(p);
}
static __device__ __forceinline__ float b2f(bf16 v) { return __bfloat162float(v); }
static __device__ __forceinline__ bf16 f2b(float v) { return __float2bfloat16(v); }
static __device__ __forceinline__ unsigned short f2bits(float v) {
  bf16 h = __float2bfloat16(v);
  unsigned short u; __builtin_memcpy(&u, &h, 2); return u;
}

// ---------------- all 4 weight transposes in one launch ----------------
// dst[n][k] = src[k][n], fp32 -> bf16
__global__ __launch_bounds__(256) void transpose_all(
    const float* __restrict__ qkv_w, const float* __restrict__ proj_w,
    const float* __restrict__ fc1_w, const float* __restrict__ fc2_w,
    bf16* __restrict__ bq, bf16* __restrict__ bp,
    bf16* __restrict__ b1, bf16* __restrict__ b2) {
  int idx = blockIdx.x * 256 + threadIdx.x;
  if (idx < 49152) {                       // qkv: K=128, N=384
    int k = idx / 384, n = idx - k * 384;
    bq[(size_t)n * 128 + k] = f2b(qkv_w[idx]);
  } else if (idx < 65536) {                // proj: K=128, N=128
    int i = idx - 49152;
    int k = i / 128, n = i - k * 128;
    bp[(size_t)n * 128 + k] = f2b(proj_w[i]);
  } else if (idx < 131072) {               // fc1: K=128, N=512
    int i = idx - 65536;
    int k = i / 512, n = i - k * 512;
    b1[(size_t)n * 128 + k] = f2b(fc1_w[i]);
  } else if (idx < 196608) {               // fc2: K=512, N=128
    int i = idx - 131072;
    int k = i / 128, n = i - k * 128;
    b2[(size_t)n * 512 + k] = f2b(fc2_w[i]);
  }
}

// ---------------- fused LN1 + cyclic shift + window gather + qkv GEMM ----------------
// Block: 64 windowed rows x 128 cols (blockIdx.y in 0..2). LN recomputed per col-group.
__global__ __launch_bounds__(256) void qkv_ln1_k(const float* __restrict__ x,
    const float* __restrict__ g, const float* __restrict__ bt,
    const bf16* __restrict__ Bt, const float* __restrict__ bias,
    bf16* __restrict__ out, int row_base) {
  __shared__ __align__(16) unsigned short xn[64][136];   // 64 rows x 128 bf16, padded
  const int lane = threadIdx.x & 63, wave = threadIdx.x >> 6;
  const int row0 = blockIdx.x * 64;

  // ---- LN phase: each wave LNs 16 rows (gather from shifted image) ----
  for (int r = 0; r < 16; r++) {
    int lrow = wave * 16 + r;
    int gid = row0 + lrow + row_base;
    int b_ = gid / 98, n = gid - b_ * 98;
    int batch = b_ >> 8, widx = b_ & 255;
    int tw = widx >> 6, hw = (widx >> 3) & 7, ww = widx & 7;
    int ti = n / 49, rr = n - ti * 49, hi = rr / 7, wi = rr - hi * 7;
    int t = (tw * 2 + ti + 1) & 7;
    int h = hw * 7 + hi + 3; if (h >= 56) h -= 56;
    int w = ww * 7 + wi + 3; if (w >= 56) w -= 56;
    const float2* src = reinterpret_cast<const float2*>(
        x + ((size_t)batch * THW + (t * 56 + h) * 56 + w) * 128);
    float2 v = src[lane];
    float s = v.x + v.y, ss = v.x * v.x + v.y * v.y;
    #pragma unroll
    for (int m = 1; m < 64; m <<= 1) { s += __shfl_xor(s, m); ss += __shfl_xor(ss, m); }
    float mu = s * (1.f / 128.f);
    float var = ss * (1.f / 128.f) - mu * mu;
    float rs = rsqrtf(var + 1e-5f);
    float2 gp = reinterpret_cast<const float2*>(g)[lane];
    float2 bp = reinterpret_cast<const float2*>(bt)[lane];
    float o0 = (v.x - mu) * rs * gp.x + bp.x;
    float o1 = (v.y - mu) * rs * gp.y + bp.y;
    *reinterpret_cast<unsigned int*>(&xn[lrow][lane * 2]) =
        (unsigned int)f2bits(o0) | ((unsigned int)f2bits(o1) << 16);
  }
  __syncthreads();

  // ---- GEMM phase: A from LDS, Bt row-major [N][K] bf16 ----
  const int l15 = lane & 15, lq = lane >> 4;
  const int wm = wave & 1, wn = wave >> 1;
  const int col0 = blockIdx.y * 128 + wn * 64;
  const bf16* Bp = Bt + (size_t)(col0 + l15) * 128 + lq * 8;
  float4f acc[2][4];
  #pragma unroll
  for (int mt = 0; mt < 2; mt++)
    #pragma unroll
    for (int nt = 0; nt < 4; nt++) acc[mt][nt] = (float4f){0.f, 0.f, 0.f, 0.f};

  #pragma unroll
  for (int k0 = 0; k0 < 128; k0 += 32) {
    short8 a0 = *reinterpret_cast<const short8*>(&xn[wm * 32 + l15][k0 + lq * 8]);
    short8 a1 = *reinterpret_cast<const short8*>(&xn[wm * 32 + 16 + l15][k0 + lq * 8]);
    #pragma unroll
    for (int nt = 0; nt < 4; nt++) {
      short8 b = load8(Bp + (size_t)nt * 16 * 128 + k0);
      acc[0][nt] = mfma16(a0, b, acc[0][nt]);
      acc[1][nt] = mfma16(a1, b, acc[1][nt]);
    }
  }
  #pragma unroll
  for (int mt = 0; mt < 2; mt++) {
    #pragma unroll
    for (int r = 0; r < 4; r++) {
      int row = row0 + wm * 32 + mt * 16 + lq * 4 + r;
      #pragma unroll
      for (int nt = 0; nt < 4; nt++) {
        int col = col0 + nt * 16 + l15;
        out[(size_t)row * 384 + col] = f2b(acc[mt][nt][r] + bias[col]);
      }
    }
  }
}

// ---------------- MFMA GEMM, Bt is [N][K] row-major bf16 (proj scatter path) --------
template<int EPI, int K>
__global__ __launch_bounds__(256) void gemm_bt(const bf16* __restrict__ A,
    const bf16* __restrict__ Bt, const float* __restrict__ bias,
    bf16* __restrict__ out_b, const float* __restrict__ resid_x,
    const float* __restrict__ resid_f, float* __restrict__ out_f,
    int row_base, int tok_base) {
  const int lane = threadIdx.x & 63, wave = threadIdx.x >> 6;
  const int l15 = lane & 15, lq = lane >> 4;
  const int wm = wave & 1, wn = wave >> 1;
  const int row0 = blockIdx.x * 64 + wm * 32;
  const int col0 = blockIdx.y * 128 + wn * 64;
  const int ldC = gridDim.y * 128;
  const bf16* Ap = A + (size_t)(row0 + l15) * K + lq * 8;
  const bf16* Bp = Bt + (size_t)(col0 + l15) * K + lq * 8;
  float4f acc[2][4];
  #pragma unroll
  for (int mt = 0; mt < 2; mt++)
    #pragma unroll
    for (int nt = 0; nt < 4; nt++) acc[mt][nt] = (float4f){0.f, 0.f, 0.f, 0.f};

  #pragma unroll
  for (int k0 = 0; k0 < K; k0 += 32) {
    short8 a0 = load8(Ap + k0);
    short8 a1 = load8(Ap + 16 * K + k0);
    #pragma unroll
    for (int nt = 0; nt < 4; nt++) {
      short8 b = load8(Bp + nt * 16 * K + k0);
      acc[0][nt] = mfma16(a0, b, acc[0][nt]);
      acc[1][nt] = mfma16(a1, b, acc[1][nt]);
    }
  }

  #pragma unroll
  for (int mt = 0; mt < 2; mt++) {
    #pragma unroll
    for (int r = 0; r < 4; r++) {
      int row = row0 + mt * 16 + lq * 4 + r;      // local row
      size_t dstLoc = 0, dstGlob = 0;
      if (EPI == 1) {
        int grow = row + row_base;
        int b_ = grow / 98, n = grow - b_ * 98;
        int batch = b_ >> 8, widx = b_ & 255;
        int tw = widx >> 6, hw = (widx >> 3) & 7, ww = widx & 7;
        int ti = n / 49, rr = n - ti * 49, hi = rr / 7, wi = rr - hi * 7;
        int t = (tw * 2 + ti + 1) & 7;
        int h = hw * 7 + hi + 3; if (h >= 56) h -= 56;
        int w = ww * 7 + wi + 3; if (w >= 56) w -= 56;
        dstGlob = (size_t)batch * THW + (t * 56 + h) * 56 + w;
        dstLoc = dstGlob - (size_t)tok_base;
      }
      #pragma unroll
      for (int nt = 0; nt < 4; nt++) {
        int col = col0 + nt * 16 + l15;
        float v = acc[mt][nt][r] + bias[col];
        if (EPI == 0) {
          out_b[(size_t)row * ldC + col] = f2b(v);
        } else if (EPI == 1) {
          out_f[dstLoc * 128 + col] = resid_x[dstGlob * 128 + col] + v;
        } else if (EPI == 2) {
          float gl = 0.5f * v * (1.f + erff(v * 0.70710678118654752f));
          out_b[(size_t)row * ldC + col] = f2b(gl);
        } else {
          out_f[(size_t)row * 128 + col] = resid_f[(size_t)row * 128 + col] + v;
        }
      }
    }
  }
}

// ---------------- attention: one wave per (window, head, 16-row block) ----------------
__global__ __launch_bounds__(256) void attn_k(const bf16* __restrict__ qkv,
    const float* __restrict__ rpb, bf16* __restrict__ outb, int wbase) {
  __shared__ __align__(16) unsigned short Pl[4][16][136];
  const int wave = threadIdx.x >> 6, lane = threadIdx.x & 63;
  const int l15 = lane & 15, lq = lane >> 4;
  int g = blockIdx.x * 4 + wave;           // 0..7167 per chunk
  int rb = g % 7; int bh = g / 7; int head = bh & 3; int bl = bh >> 2;
  int bg = bl + wbase;
  int q0 = rb * 16;
  const bf16* base = qkv + (size_t)bl * 98 * 384;
  const unsigned short* base_u = reinterpret_cast<const unsigned short*>(base);

  // Q fragment (A operand): A[m=l15][k=lq*8+j]
  int qrow = q0 + l15; if (qrow > 97) qrow = 97;
  short8 aq = load8(base + (size_t)qrow * 384 + head * 32 + lq * 8);

  // S = Q K^T : 7 col-tiles, one MFMA each (K=HD=32)
  float4f s[7];
  #pragma unroll
  for (int t = 0; t < 7; t++) {
    int kr = t * 16 + l15; if (kr > 97) kr = 97;
    short8 kb = load8(base + (size_t)kr * 384 + 128 + head * 32 + lq * 8);
    s[t] = mfma16(aq, kb, (float4f){0.f, 0.f, 0.f, 0.f});
  }

  int widx = bg & 255;
  int tw = widx >> 6, hw = (widx >> 3) & 7, ww = widx & 7;
  int iti[4], ihi[4], iwi[4], ilab[4];
  #pragma unroll
  for (int r = 0; r < 4; r++) {
    int i = q0 + lq * 4 + r; if (i > 97) i = 97;
    int ti = i / 49, rr = i - ti * 49, hi = rr / 7, wi = rr - hi * 7;
    iti[r] = ti; ihi[r] = hi; iwi[r] = wi;
    int tg = tw * 2 + ti, hg = hw * 7 + hi, wg = ww * 7 + wi;
    ilab[r] = ((tg >= 6) + (tg >= 7)) * 9 + ((hg >= 49) + (hg >= 53)) * 3 +
              ((wg >= 49) + (wg >= 53));
  }

  float pv[7][4];
  #pragma unroll
  for (int t = 0; t < 7; t++) {
    int j = t * 16 + l15;
    bool jvalid = (j < 98); int jc = jvalid ? j : 97;
    int tj = jc / 49, rr = jc - tj * 49, hj = rr / 7, wj = rr - hj * 7;
    int tg = tw * 2 + tj, hg = hw * 7 + hj, wg = ww * 7 + wj;
    int jlab = ((tg >= 6) + (tg >= 7)) * 9 + ((hg >= 49) + (hg >= 53)) * 3 +
               ((wg >= 49) + (wg >= 53));
    #pragma unroll
    for (int r = 0; r < 4; r++) {
      int idx = (iti[r] - tj + 1) * 169 + (ihi[r] - hj + 6) * 13 + (iwi[r] - wj + 6);
      float v = s[t][r] * SCALE_QK + rpb[idx * 4 + head];
      if (ilab[r] != jlab) v -= 100.f;
      if (!jvalid) v = -30000.f;
      pv[t][r] = v;
    }
  }

  // exact softmax over the full 112-col row held in registers
  #pragma unroll
  for (int r = 0; r < 4; r++) {
    float m = pv[0][r];
    #pragma unroll
    for (int t = 1; t < 7; t++) m = fmaxf(m, pv[t][r]);
    #pragma unroll
    for (int d = 1; d < 16; d <<= 1) m = fmaxf(m, __shfl_xor(m, d));
    float sum = 0.f;
    #pragma unroll
    for (int t = 0; t < 7; t++) { float p = __expf(pv[t][r] - m); pv[t][r] = p; sum += p; }
    #pragma unroll
    for (int d = 1; d < 16; d <<= 1) sum += __shfl_xor(sum, d);
    float inv = 1.f / sum;
    int prow = lq * 4 + r;
    #pragma unroll
    for (int t = 0; t < 7; t++) Pl[wave][prow][t * 16 + l15] = f2bits(pv[t][r] * inv);
    Pl[wave][prow][112 + l15] = 0;   // zero-pad cols 112..127
  }

  __syncthreads();

  // O = P V : K padded to 128 (P zero there)
  float4f o[2];
  o[0] = (float4f){0.f, 0.f, 0.f, 0.f};
  o[1] = (float4f){0.f, 0.f, 0.f, 0.f};
  #pragma unroll
  for (int ks = 0; ks < 4; ks++) {
    short8 ap = *reinterpret_cast<const short8*>(&Pl[wave][l15][ks * 32 + lq * 8]);
    #pragma unroll
    for (int dt = 0; dt < 2; dt++) {
      short8 vb;
      #pragma unroll
      for (int j = 0; j < 8; j++) {
        int vr = ks * 32 + lq * 8 + j; if (vr > 97) vr = 97;
        vb[j] = (short)base_u[(size_t)vr * 384 + 256 + head * 32 + dt * 16 + l15];
      }
      o[dt] = mfma16(ap, vb, o[dt]);
    }
  }
  #pragma unroll
  for (int dt = 0; dt < 2; dt++) {
    #pragma unroll
    for (int r = 0; r < 4; r++) {
      int row = q0 + lq * 4 + r;
      if (row < 98)
        outb[((size_t)bl * 98 + row) * 128 + head * 32 + dt * 16 + l15] = f2b(o[dt][r]);
    }
  }
}

// ---------------- fused LN2 + fc1 + GELU + fc2 + residual ----------------
// Block: 64 rows. LN into LDS; then 4 hidden-chunks of 128:
//   GEMM1 (64x128, K=128) -> GELU -> LDS hid -> GEMM2 accumulate (64x128, K-chunk 128)
__global__ __launch_bounds__(256) void mlp_k(const float* __restrict__ xmid,
    const float* __restrict__ g, const float* __restrict__ bt,
    const bf16* __restrict__ fc1t, const float* __restrict__ fc1b,
    const bf16* __restrict__ fc2t, const float* __restrict__ fc2b,
    float* __restrict__ out) {
  __shared__ __align__(16) unsigned short xn[64][136];
  __shared__ __align__(16) unsigned short hid[64][136];
  const int lane = threadIdx.x & 63, wave = threadIdx.x >> 6;
  const int l15 = lane & 15, lq = lane >> 4;
  const int wm = wave & 1, wn = wave >> 1;
  const int row0 = blockIdx.x * 64;

  // ---- LN2 phase: each wave LNs 16 rows ----
  for (int r = 0; r < 16; r++) {
    int lrow = wave * 16 + r;
    const float2* src = reinterpret_cast<const float2*>(xmid + (size_t)(row0 + lrow) * 128);
    float2 v = src[lane];
    float s = v.x + v.y, ss = v.x * v.x + v.y * v.y;
    #pragma unroll
    for (int m = 1; m < 64; m <<= 1) { s += __shfl_xor(s, m); ss += __shfl_xor(ss, m); }
    float mu = s * (1.f / 128.f);
    float var = ss * (1.f / 128.f) - mu * mu;
    float rs = rsqrtf(var + 1e-5f);
    float2 gp = reinterpret_cast<const float2*>(g)[lane];
    float2 bp = reinterpret_cast<const float2*>(bt)[lane];
    float o0 = (v.x - mu) * rs * gp.x + bp.x;
    float o1 = (v.y - mu) * rs * gp.y + bp.y;
    *reinterpret_cast<unsigned int*>(&xn[lrow][lane * 2]) =
        (unsigned int)f2bits(o0) | ((unsigned int)f2bits(o1) << 16);
  }
  __syncthreads();

  float4f acc2[2][4];
  #pragma unroll
  for (int mt = 0; mt < 2; mt++)
    #pragma unroll
    for (int nt = 0; nt < 4; nt++) acc2[mt][nt] = (float4f){0.f, 0.f, 0.f, 0.f};

  #pragma unroll
  for (int hb = 0; hb < 4; hb++) {
    // ---- GEMM1: hidden chunk [64 rows][128 cols], wave tile 32x64 ----
    float4f acc1[2][4];
    #pragma unroll
    for (int mt = 0; mt < 2; mt++)
      #pragma unroll
      for (int nt = 0; nt < 4; nt++) acc1[mt][nt] = (float4f){0.f, 0.f, 0.f, 0.f};
    const bf16* B1 = fc1t + (size_t)(hb * 128 + wn * 64 + l15) * 128 + lq * 8;
    #pragma unroll
    for (int k0 = 0; k0 < 128; k0 += 32) {
      short8 a0 = *reinterpret_cast<const short8*>(&xn[wm * 32 + l15][k0 + lq * 8]);
      short8 a1 = *reinterpret_cast<const short8*>(&xn[wm * 32 + 16 + l15][k0 + lq * 8]);
      #pragma unroll
      for (int nt = 0; nt < 4; nt++) {
        short8 b = load8(B1 + (size_t)nt * 16 * 128 + k0);
        acc1[0][nt] = mfma16(a0, b, acc1[0][nt]);
        acc1[1][nt] = mfma16(a1, b, acc1[1][nt]);
      }
    }
    if (hb) __syncthreads();   // all waves done reading hid from previous chunk
    // ---- GELU + pack to LDS hid ----
    #pragma unroll
    for (int mt = 0; mt < 2; mt++) {
      #pragma unroll
      for (int nt = 0; nt < 4; nt++) {
        #pragma unroll
        for (int r = 0; r < 4; r++) {
          int hr = wm * 32 + mt * 16 + lq * 4 + r;
          int hc = wn * 64 + nt * 16 + l15;
          float v = acc1[mt][nt][r] + fc1b[hb * 128 + hc];
          float gl = 0.5f * v * (1.f + erff(v * 0.70710678118654752f));
          hid[hr][hc] = f2bits(gl);
        }
      }
    }
    __syncthreads();
    // ---- GEMM2: accumulate out[64x128] over this K-chunk of 128 ----
    const bf16* B2 = fc2t + (size_t)(wn * 64 + l15) * 512 + hb * 128 + lq * 8;
    #pragma unroll
    for (int k0 = 0; k0 < 128; k0 += 32) {
      short8 a0 = *reinterpret_cast<const short8*>(&hid[wm * 32 + l15][k0 + lq * 8]);
      short8 a1 = *reinterpret_cast<const short8*>(&hid[wm * 32 + 16 + l15][k0 + lq * 8]);
      #pragma unroll
      for (int nt = 0; nt < 4; nt++) {
        short8 b = load8(B2 + (size_t)nt * 16 * 512 + k0);
        acc2[0][nt] = mfma16(a0, b, acc2[0][nt]);
        acc2[1][nt] = mfma16(a1, b, acc2[1][nt]);
      }
    }
  }

  // ---- epilogue: + fc2 bias + residual(xmid) -> fp32 out ----
  #pragma unroll
  for (int mt = 0; mt < 2; mt++) {
    #pragma unroll
    for (int r = 0; r < 4; r++) {
      int row = row0 + wm * 32 + mt * 16 + lq * 4 + r;
      #pragma unroll
      for (int nt = 0; nt < 4; nt++) {
        int col = wn * 64 + nt * 16 + l15;
        float v = acc2[mt][nt][r] + fc2b[col];
        out[(size_t)row * 128 + col] = xmid[(size_t)row * 128 + col] + v;
      }
    }
  }
}

extern "C" void kernel_launch(void* const* d_in, const int* in_sizes, int n_in,
                              void* d_out, int out_size, void* d_ws, size_t ws_size,
                              hipStream_t stream) {
  (void)in_sizes; (void)n_in; (void)out_size; (void)ws_size;
  const float* x      = (const float*)d_in[0];
  const float* n1g    = (const float*)d_in[1];
  const float* n1b    = (const float*)d_in[2];
  const float* qkv_w  = (const float*)d_in[3];
  const float* qkv_b  = (const float*)d_in[4];
  const float* proj_w = (const float*)d_in[5];
  const float* proj_b = (const float*)d_in[6];
  const float* rpb    = (const float*)d_in[7];
  const float* n2g    = (const float*)d_in[8];
  const float* n2b    = (const float*)d_in[9];
  const float* fc1_w  = (const float*)d_in[10];
  const float* fc1_b  = (const float*)d_in[11];
  const float* fc2_w  = (const float*)d_in[12];
  const float* fc2_b  = (const float*)d_in[13];
  float* out = (float*)d_out;

  char* ws = (char*)d_ws;
  bf16* bt_qkv  = (bf16*)(ws + 0);        //  98304 B
  bf16* bt_proj = (bf16*)(ws + 98304);    //  32768 B
  bf16* bt_fc1  = (bf16*)(ws + 131072);   // 131072 B
  bf16* bt_fc2  = (bf16*)(ws + 262144);   // 131072 B
  bf16*  R0c  = (bf16*)(ws + 393216);                  //  6,422,528 B (attn out)
  float* xmid = (float*)(ws + 393216 + 6422528);       // 12,845,056 B
  bf16*  Zq   = (bf16*)(ws + 393216 + 19267584);       // 19,267,584 B (qkv)
  // peak ws ~= 38.9 MB

  transpose_all<<<768, 256, 0, stream>>>(qkv_w, proj_w, fc1_w, fc2_w,
                                         bt_qkv, bt_proj, bt_fc1, bt_fc2);

  for (int c = 0; c < 8; c++) {
    const int row_base = c * CH_ROWS;
    const int tok_base = c * THW;
    const int wbase = c * 256;

    // LN1 + shift + partition + qkv -> Zq [CH_ROWS x 384] bf16
    qkv_ln1_k<<<dim3(392, 3), 256, 0, stream>>>(x, n1g, n1b, bt_qkv, qkv_b,
                                                Zq, row_base);

    // attention -> R0c (windowed order) bf16
    attn_k<<<1792, 256, 0, stream>>>(Zq, rpb, R0c, wbase);

    // proj + window-reverse/unshift scatter + residual(x) -> xmid fp32 (natural)
    gemm_bt<1, 128><<<dim3(392, 1), 256, 0, stream>>>(R0c, bt_proj, proj_b,
        nullptr, x, nullptr, xmid, row_base, tok_base);

    // LN2 + fc1 + GELU + fc2 + residual(xmid) -> fp32 out chunk
    mlp_k<<<392, 256, 0, stream>>>(xmid, n2g, n2b, bt_fc1, fc1_b, bt_fc2, fc2_b,
                                   out + (size_t)tok_base * 128);
  }
}

// Round 2
// 778.241 us; speedup vs baseline: 1.4637x; 1.3231x over previous
//
#include <hip/hip_runtime.h>
#include <hip/hip_bf16.h>
#include <cmath>

using bf16 = __hip_bfloat16;
typedef __attribute__((ext_vector_type(8))) short short8;
typedef __attribute__((ext_vector_type(4))) float float4f;

#define THW 25088           // tokens per batch
#define SCALE_QK 0.17677669529663687f

static __device__ __forceinline__ float4f mfma16(short8 a, short8 b, float4f c) {
  return __builtin_amdgcn_mfma_f32_16x16x32_bf16(a, b, c, 0, 0, 0);
}
static __device__ __forceinline__ short8 load8(const bf16* p) {
  return *reinterpret_cast<const short8*>(p);
}
static __device__ __forceinline__ short8 load8u(const unsigned short* p) {
  return *reinterpret_cast<const short8*>(p);
}
static __device__ __forceinline__ bf16 f2b(float v) { return __float2bfloat16(v); }
static __device__ __forceinline__ unsigned short f2bits(float v) {
  bf16 h = __float2bfloat16(v);
  unsigned short u; __builtin_memcpy(&u, &h, 2); return u;
}

// ---------------- all 4 weight transposes in one launch ----------------
// dst[n][k] = src[k][n], fp32 -> bf16
__global__ __launch_bounds__(256) void transpose_all(
    const float* __restrict__ qkv_w, const float* __restrict__ proj_w,
    const float* __restrict__ fc1_w, const float* __restrict__ fc2_w,
    bf16* __restrict__ bq, bf16* __restrict__ bp,
    bf16* __restrict__ b1, bf16* __restrict__ b2) {
  int idx = blockIdx.x * 256 + threadIdx.x;
  if (idx < 49152) {                       // qkv: K=128, N=384
    int k = idx / 384, n = idx - k * 384;
    bq[(size_t)n * 128 + k] = f2b(qkv_w[idx]);
  } else if (idx < 65536) {                // proj: K=128, N=128
    int i = idx - 49152;
    int k = i / 128, n = i - k * 128;
    bp[(size_t)n * 128 + k] = f2b(proj_w[i]);
  } else if (idx < 131072) {               // fc1: K=128, N=512
    int i = idx - 65536;
    int k = i / 512, n = i - k * 512;
    b1[(size_t)n * 128 + k] = f2b(fc1_w[i]);
  } else if (idx < 196608) {               // fc2: K=512, N=128
    int i = idx - 131072;
    int k = i / 128, n = i - k * 128;
    b2[(size_t)n * 512 + k] = f2b(fc2_w[i]);
  }
}

// =====================================================================
// win_k: one block per window (2048 windows, all 8 batches).
// Entire attention pipeline in LDS:
//   LN1+shift+gather -> QKV GEMM -> attention -> proj + scatter + residual(x)
// Writes xmid (= proj out + residual) directly into `out` buffer.
// =====================================================================
__global__ __launch_bounds__(512) void win_k(const float* __restrict__ x,
    const float* __restrict__ n1g, const float* __restrict__ n1b,
    const bf16* __restrict__ bt_qkv, const float* __restrict__ qkv_b,
    const bf16* __restrict__ bt_proj, const float* __restrict__ proj_b,
    const float* __restrict__ rpb, float* __restrict__ out) {
  // LDS: 30464 + 59136 + 34816 + 34816 = 159232 B (<= 160 KiB)
  __shared__ __align__(16) unsigned short xn[112][136];   // LN'd input; later attn-out
  __shared__ __align__(16) unsigned short qk[112][264];   // Q cols 0..127, K cols 128..255
  __shared__ __align__(16) unsigned short vt[128][136];   // V transposed: [d][k]
  __shared__ __align__(16) unsigned short Pl[8][16][136]; // per-wave P buffer

  const int lane = threadIdx.x & 63, wave = threadIdx.x >> 6;
  const int l15 = lane & 15, lq = lane >> 4;
  const int wg = blockIdx.x;
  const int batch = wg >> 8, widx = wg & 255;
  const int tw = widx >> 6, hw = (widx >> 3) & 7, ww = widx & 7;

  // zero vt k-columns 112..135 (never written by QKV epilogue; read by PV with P=0)
  for (int i = threadIdx.x; i < 128 * 24; i += 512) {
    int d = i / 24, c = 112 + i % 24;
    vt[d][c] = 0;
  }

  // ---- phase 1: LN1 + shift + window gather (112 padded rows; pad = clone row 97)
  for (int rr_ = 0; rr_ < 14; rr_++) {
    int lrow = wave * 14 + rr_;
    int n = lrow > 97 ? 97 : lrow;
    int ti = n / 49, rr = n - ti * 49, hi = rr / 7, wi = rr - hi * 7;
    int t = (tw * 2 + ti + 1) & 7;
    int h = hw * 7 + hi + 3; if (h >= 56) h -= 56;
    int w = ww * 7 + wi + 3; if (w >= 56) w -= 56;
    const float2* src = reinterpret_cast<const float2*>(
        x + ((size_t)batch * THW + (t * 56 + h) * 56 + w) * 128);
    float2 v = src[lane];
    float s = v.x + v.y, ss = v.x * v.x + v.y * v.y;
    #pragma unroll
    for (int m = 1; m < 64; m <<= 1) { s += __shfl_xor(s, m); ss += __shfl_xor(ss, m); }
    float mu = s * (1.f / 128.f);
    float var = ss * (1.f / 128.f) - mu * mu;
    float rs = rsqrtf(var + 1e-5f);
    float2 gp = reinterpret_cast<const float2*>(n1g)[lane];
    float2 bp = reinterpret_cast<const float2*>(n1b)[lane];
    float o0 = (v.x - mu) * rs * gp.x + bp.x;
    float o1 = (v.y - mu) * rs * gp.y + bp.y;
    *reinterpret_cast<unsigned int*>(&xn[lrow][lane * 2]) =
        (unsigned int)f2bits(o0) | ((unsigned int)f2bits(o1) << 16);
  }
  __syncthreads();

  // ---- phase 2: QKV GEMM (112x384, K=128). wave w -> cols [w*48, w*48+48)
  {
    const int cw = wave * 48;
    float bs[3];
    #pragma unroll
    for (int ct = 0; ct < 3; ct++) bs[ct] = qkv_b[cw + ct * 16 + l15];
    for (int rt = 0; rt < 7; rt++) {
      short8 a[4];
      #pragma unroll
      for (int q = 0; q < 4; q++)
        a[q] = load8u(&xn[rt * 16 + l15][q * 32 + lq * 8]);
      #pragma unroll
      for (int ct = 0; ct < 3; ct++) {
        const int colb = cw + ct * 16;
        const bf16* Bp = bt_qkv + (size_t)(colb + l15) * 128 + lq * 8;
        float4f acc = (float4f){0.f, 0.f, 0.f, 0.f};
        #pragma unroll
        for (int q = 0; q < 4; q++) acc = mfma16(a[q], load8(Bp + q * 32), acc);
        const int col = colb + l15;
        #pragma unroll
        for (int r = 0; r < 4; r++) {
          int row = rt * 16 + lq * 4 + r;
          unsigned short hv = f2bits(acc[r] + bs[ct]);
          if (colb < 256) qk[row][col] = hv;
          else            vt[col - 256][row] = hv;
        }
      }
    }
  }
  __syncthreads();

  // ---- phase 3: attention. 28 wave-tasks = (head 0..3) x (row-block 0..6)
  for (int task = wave; task < 28; task += 8) {
    const int head = task & 3, rb = task >> 2;
    const int q0 = rb * 16;

    short8 aq = load8u(&qk[q0 + l15][head * 32 + lq * 8]);
    float4f s[7];
    #pragma unroll
    for (int t = 0; t < 7; t++) {
      short8 kb = load8u(&qk[t * 16 + l15][128 + head * 32 + lq * 8]);
      s[t] = mfma16(aq, kb, (float4f){0.f, 0.f, 0.f, 0.f});
    }

    int iti[4], ihi[4], iwi[4], ilab[4];
    #pragma unroll
    for (int r = 0; r < 4; r++) {
      int i = q0 + lq * 4 + r; if (i > 97) i = 97;
      int ti = i / 49, rr = i - ti * 49, hi = rr / 7, wi = rr - hi * 7;
      iti[r] = ti; ihi[r] = hi; iwi[r] = wi;
      int tg = tw * 2 + ti, hg = hw * 7 + hi, wg2 = ww * 7 + wi;
      ilab[r] = ((tg >= 6) + (tg >= 7)) * 9 + ((hg >= 49) + (hg >= 53)) * 3 +
                ((wg2 >= 49) + (wg2 >= 53));
    }

    float pv[7][4];
    #pragma unroll
    for (int t = 0; t < 7; t++) {
      int j = t * 16 + l15;
      bool jvalid = (j < 98); int jc = jvalid ? j : 97;
      int tj = jc / 49, rr = jc - tj * 49, hj = rr / 7, wj = rr - hj * 7;
      int tg = tw * 2 + tj, hg = hw * 7 + hj, wg2 = ww * 7 + wj;
      int jlab = ((tg >= 6) + (tg >= 7)) * 9 + ((hg >= 49) + (hg >= 53)) * 3 +
                 ((wg2 >= 49) + (wg2 >= 53));
      #pragma unroll
      for (int r = 0; r < 4; r++) {
        int idx = (iti[r] - tj + 1) * 169 + (ihi[r] - hj + 6) * 13 + (iwi[r] - wj + 6);
        float v = s[t][r] * SCALE_QK + rpb[idx * 4 + head];
        if (ilab[r] != jlab) v -= 100.f;
        if (!jvalid) v = -30000.f;
        pv[t][r] = v;
      }
    }

    // exact softmax over the 112-col row (cols >=98 are -30000 -> 0)
    #pragma unroll
    for (int r = 0; r < 4; r++) {
      float m = pv[0][r];
      #pragma unroll
      for (int t = 1; t < 7; t++) m = fmaxf(m, pv[t][r]);
      #pragma unroll
      for (int d = 1; d < 16; d <<= 1) m = fmaxf(m, __shfl_xor(m, d));
      float sum = 0.f;
      #pragma unroll
      for (int t = 0; t < 7; t++) { float p = __expf(pv[t][r] - m); pv[t][r] = p; sum += p; }
      #pragma unroll
      for (int d = 1; d < 16; d <<= 1) sum += __shfl_xor(sum, d);
      float inv = 1.f / sum;
      int prow = lq * 4 + r;
      #pragma unroll
      for (int t = 0; t < 7; t++) Pl[wave][prow][t * 16 + l15] = f2bits(pv[t][r] * inv);
      Pl[wave][prow][112 + l15] = 0;   // zero-pad cols 112..127
    }

    // O = P V  (V from vt, transposed layout -> contiguous b128 B-fragments)
    float4f o[2];
    o[0] = (float4f){0.f, 0.f, 0.f, 0.f};
    o[1] = (float4f){0.f, 0.f, 0.f, 0.f};
    #pragma unroll
    for (int ks = 0; ks < 4; ks++) {
      short8 ap = load8u(&Pl[wave][l15][ks * 32 + lq * 8]);
      #pragma unroll
      for (int dt = 0; dt < 2; dt++) {
        short8 vb = load8u(&vt[head * 32 + dt * 16 + l15][ks * 32 + lq * 8]);
        o[dt] = mfma16(ap, vb, o[dt]);
      }
    }
    // write attn-out into xn (rows 98..111 are finite clones; discarded later)
    #pragma unroll
    for (int dt = 0; dt < 2; dt++) {
      #pragma unroll
      for (int r = 0; r < 4; r++) {
        xn[q0 + lq * 4 + r][head * 32 + dt * 16 + l15] = f2bits(o[dt][r]);
      }
    }
  }
  __syncthreads();

  // ---- phase 4: proj (112x128, K=128) + scatter/unshift + residual(x) -> out
  {
    const int wn = wave & 3;               // col group of 32
    const int wmh = wave >> 2;             // row half: 0 -> rt 0..3, 1 -> rt 4..6
    const int rt0 = wmh ? 4 : 0, rt1 = wmh ? 7 : 4;
    float pb[2];
    #pragma unroll
    for (int ct = 0; ct < 2; ct++) pb[ct] = proj_b[wn * 32 + ct * 16 + l15];
    for (int rt = rt0; rt < rt1; rt++) {
      short8 a[4];
      #pragma unroll
      for (int q = 0; q < 4; q++)
        a[q] = load8u(&xn[rt * 16 + l15][q * 32 + lq * 8]);
      #pragma unroll
      for (int ct = 0; ct < 2; ct++) {
        const int colb = wn * 32 + ct * 16;
        const bf16* Bp = bt_proj + (size_t)(colb + l15) * 128 + lq * 8;
        float4f acc = (float4f){0.f, 0.f, 0.f, 0.f};
        #pragma unroll
        for (int q = 0; q < 4; q++) acc = mfma16(a[q], load8(Bp + q * 32), acc);
        const int col = colb + l15;
        #pragma unroll
        for (int r = 0; r < 4; r++) {
          int row = rt * 16 + lq * 4 + r;
          if (row < 98) {
            int ti = row / 49, rr = row - ti * 49, hi = rr / 7, wi = rr - hi * 7;
            int t = (tw * 2 + ti + 1) & 7;
            int h = hw * 7 + hi + 3; if (h >= 56) h -= 56;
            int w = ww * 7 + wi + 3; if (w >= 56) w -= 56;
            size_t dstGlob = (size_t)batch * THW + (t * 56 + h) * 56 + w;
            out[dstGlob * 128 + col] = x[dstGlob * 128 + col] + acc[r] + pb[ct];
          }
        }
      }
    }
  }
}

// ---------------- fused LN2 + fc1 + GELU + fc2 + residual (in-place on out) --------
__global__ __launch_bounds__(256) void mlp_k(const float* xmid,
    const float* __restrict__ g, const float* __restrict__ bt,
    const bf16* __restrict__ fc1t, const float* __restrict__ fc1b,
    const bf16* __restrict__ fc2t, const float* __restrict__ fc2b,
    float* out) {
  __shared__ __align__(16) unsigned short xn[64][136];
  __shared__ __align__(16) unsigned short hid[64][136];
  const int lane = threadIdx.x & 63, wave = threadIdx.x >> 6;
  const int l15 = lane & 15, lq = lane >> 4;
  const int wm = wave & 1, wn = wave >> 1;
  const int row0 = blockIdx.x * 64;

  for (int r = 0; r < 16; r++) {
    int lrow = wave * 16 + r;
    const float2* src = reinterpret_cast<const float2*>(xmid + (size_t)(row0 + lrow) * 128);
    float2 v = src[lane];
    float s = v.x + v.y, ss = v.x * v.x + v.y * v.y;
    #pragma unroll
    for (int m = 1; m < 64; m <<= 1) { s += __shfl_xor(s, m); ss += __shfl_xor(ss, m); }
    float mu = s * (1.f / 128.f);
    float var = ss * (1.f / 128.f) - mu * mu;
    float rs = rsqrtf(var + 1e-5f);
    float2 gp = reinterpret_cast<const float2*>(g)[lane];
    float2 bp = reinterpret_cast<const float2*>(bt)[lane];
    float o0 = (v.x - mu) * rs * gp.x + bp.x;
    float o1 = (v.y - mu) * rs * gp.y + bp.y;
    *reinterpret_cast<unsigned int*>(&xn[lrow][lane * 2]) =
        (unsigned int)f2bits(o0) | ((unsigned int)f2bits(o1) << 16);
  }
  __syncthreads();

  float4f acc2[2][4];
  #pragma unroll
  for (int mt = 0; mt < 2; mt++)
    #pragma unroll
    for (int nt = 0; nt < 4; nt++) acc2[mt][nt] = (float4f){0.f, 0.f, 0.f, 0.f};

  #pragma unroll
  for (int hb = 0; hb < 4; hb++) {
    float4f acc1[2][4];
    #pragma unroll
    for (int mt = 0; mt < 2; mt++)
      #pragma unroll
      for (int nt = 0; nt < 4; nt++) acc1[mt][nt] = (float4f){0.f, 0.f, 0.f, 0.f};
    const bf16* B1 = fc1t + (size_t)(hb * 128 + wn * 64 + l15) * 128 + lq * 8;
    #pragma unroll
    for (int k0 = 0; k0 < 128; k0 += 32) {
      short8 a0 = load8u(&xn[wm * 32 + l15][k0 + lq * 8]);
      short8 a1 = load8u(&xn[wm * 32 + 16 + l15][k0 + lq * 8]);
      #pragma unroll
      for (int nt = 0; nt < 4; nt++) {
        short8 b = load8(B1 + (size_t)nt * 16 * 128 + k0);
        acc1[0][nt] = mfma16(a0, b, acc1[0][nt]);
        acc1[1][nt] = mfma16(a1, b, acc1[1][nt]);
      }
    }
    if (hb) __syncthreads();
    #pragma unroll
    for (int mt = 0; mt < 2; mt++) {
      #pragma unroll
      for (int nt = 0; nt < 4; nt++) {
        #pragma unroll
        for (int r = 0; r < 4; r++) {
          int hr = wm * 32 + mt * 16 + lq * 4 + r;
          int hc = wn * 64 + nt * 16 + l15;
          float v = acc1[mt][nt][r] + fc1b[hb * 128 + hc];
          float gl = 0.5f * v * (1.f + erff(v * 0.70710678118654752f));
          hid[hr][hc] = f2bits(gl);
        }
      }
    }
    __syncthreads();
    const bf16* B2 = fc2t + (size_t)(wn * 64 + l15) * 512 + hb * 128 + lq * 8;
    #pragma unroll
    for (int k0 = 0; k0 < 128; k0 += 32) {
      short8 a0 = load8u(&hid[wm * 32 + l15][k0 + lq * 8]);
      short8 a1 = load8u(&hid[wm * 32 + 16 + l15][k0 + lq * 8]);
      #pragma unroll
      for (int nt = 0; nt < 4; nt++) {
        short8 b = load8(B2 + (size_t)nt * 16 * 512 + k0);
        acc2[0][nt] = mfma16(a0, b, acc2[0][nt]);
        acc2[1][nt] = mfma16(a1, b, acc2[1][nt]);
      }
    }
  }

  #pragma unroll
  for (int mt = 0; mt < 2; mt++) {
    #pragma unroll
    for (int r = 0; r < 4; r++) {
      int row = row0 + wm * 32 + mt * 16 + lq * 4 + r;
      #pragma unroll
      for (int nt = 0; nt < 4; nt++) {
        int col = wn * 64 + nt * 16 + l15;
        float v = acc2[mt][nt][r] + fc2b[col];
        out[(size_t)row * 128 + col] = xmid[(size_t)row * 128 + col] + v;
      }
    }
  }
}

extern "C" void kernel_launch(void* const* d_in, const int* in_sizes, int n_in,
                              void* d_out, int out_size, void* d_ws, size_t ws_size,
                              hipStream_t stream) {
  (void)in_sizes; (void)n_in; (void)out_size; (void)ws_size;
  const float* x      = (const float*)d_in[0];
  const float* n1g    = (const float*)d_in[1];
  const float* n1b    = (const float*)d_in[2];
  const float* qkv_w  = (const float*)d_in[3];
  const float* qkv_b  = (const float*)d_in[4];
  const float* proj_w = (const float*)d_in[5];
  const float* proj_b = (const float*)d_in[6];
  const float* rpb    = (const float*)d_in[7];
  const float* n2g    = (const float*)d_in[8];
  const float* n2b    = (const float*)d_in[9];
  const float* fc1_w  = (const float*)d_in[10];
  const float* fc1_b  = (const float*)d_in[11];
  const float* fc2_w  = (const float*)d_in[12];
  const float* fc2_b  = (const float*)d_in[13];
  float* out = (float*)d_out;

  char* ws = (char*)d_ws;
  bf16* bt_qkv  = (bf16*)(ws + 0);        //  98304 B
  bf16* bt_proj = (bf16*)(ws + 98304);    //  32768 B
  bf16* bt_fc1  = (bf16*)(ws + 131072);   // 131072 B
  bf16* bt_fc2  = (bf16*)(ws + 262144);   // 131072 B
  // total ws: 393216 B — no big intermediates anymore

  transpose_all<<<768, 256, 0, stream>>>(qkv_w, proj_w, fc1_w, fc2_w,
                                         bt_qkv, bt_proj, bt_fc1, bt_fc2);

  // whole attention pipeline, all 8 batches, one launch; xmid lands in `out`
  win_k<<<2048, 512, 0, stream>>>(x, n1g, n1b, bt_qkv, qkv_b, bt_proj, proj_b,
                                  rpb, out);

  // LN2 + fc1 + GELU + fc2 + residual, in place on `out`
  mlp_k<<<3136, 256, 0, stream>>>(out, n2g, n2b, bt_fc1, fc1_b, bt_fc2, fc2_b, out);
}

// Round 3
// 651.476 us; speedup vs baseline: 1.7485x; 1.1946x over previous
//
#include <hip/hip_runtime.h>
#include <hip/hip_bf16.h>
#include <cmath>

using bf16 = __hip_bfloat16;
typedef __attribute__((ext_vector_type(8))) short short8;
typedef __attribute__((ext_vector_type(4))) float float4f;

#define THW 25088           // tokens per batch
#define SCALE_QK 0.17677669529663687f

static __device__ __forceinline__ float4f mfma16(short8 a, short8 b, float4f c) {
  return __builtin_amdgcn_mfma_f32_16x16x32_bf16(a, b, c, 0, 0, 0);
}
static __device__ __forceinline__ short8 load8(const bf16* p) {
  return *reinterpret_cast<const short8*>(p);
}
static __device__ __forceinline__ short8 load8u(const unsigned short* p) {
  return *reinterpret_cast<const short8*>(p);
}
static __device__ __forceinline__ bf16 f2b(float v) { return __float2bfloat16(v); }
static __device__ __forceinline__ unsigned short f2bits(float v) {
  bf16 h = __float2bfloat16(v);
  unsigned short u; __builtin_memcpy(&u, &h, 2); return u;
}
static __device__ __forceinline__ float bits2f(unsigned short u) {
  unsigned int w = ((unsigned int)u) << 16;
  float f; __builtin_memcpy(&f, &w, 4); return f;
}

// ---------------- weight transposes + attention bias/mask table ----------------
// weights: dst[n][k] = src[k][n], fp32 -> bf16
// table:   tbl[cat][head][row 112][col 120] bf16 = rpb + mask(cat) + (-30000 pad)
__global__ __launch_bounds__(256) void transpose_all(
    const float* __restrict__ qkv_w, const float* __restrict__ proj_w,
    const float* __restrict__ fc1_w, const float* __restrict__ fc2_w,
    const float* __restrict__ rpb,
    bf16* __restrict__ bq, bf16* __restrict__ bp,
    bf16* __restrict__ b1, bf16* __restrict__ b2,
    unsigned short* __restrict__ tbl) {
  int idx = blockIdx.x * 256 + threadIdx.x;
  if (idx < 49152) {                       // qkv: K=128, N=384
    int k = idx / 384, n = idx - k * 384;
    bq[(size_t)n * 128 + k] = f2b(qkv_w[idx]);
  } else if (idx < 65536) {                // proj: K=128, N=128
    int i = idx - 49152;
    int k = i / 128, n = i - k * 128;
    bp[(size_t)n * 128 + k] = f2b(proj_w[i]);
  } else if (idx < 131072) {               // fc1: K=128, N=512
    int i = idx - 65536;
    int k = i / 512, n = i - k * 512;
    b1[(size_t)n * 128 + k] = f2b(fc1_w[i]);
  } else if (idx < 196608) {               // fc2: K=512, N=128
    int i = idx - 131072;
    int k = i / 128, n = i - k * 128;
    b2[(size_t)n * 512 + k] = f2b(fc2_w[i]);
  } else {                                 // bias table: 8*4*112*120 entries
    int i2 = idx - 196608;
    int col = i2 % 120; int rest = i2 / 120;
    int row = rest % 112; rest /= 112;
    int head = rest & 3; int cat = rest >> 2;
    int i = row > 97 ? 97 : row;
    int j = col > 97 ? 97 : col;
    int ti = i / 49, ri = i - ti * 49, hi = ri / 7, wi = ri - hi * 7;
    int tj = j / 49, rj = j - tj * 49, hj = rj / 7, wj = rj - hj * 7;
    int tbit = (cat >> 2) & 1, hbit = (cat >> 1) & 1, wbit = cat & 1;
    int ilab = (tbit ? 1 + ti : 0) * 9 + (hbit ? 1 + (hi >= 4) : 0) * 3 +
               (wbit ? 1 + (wi >= 4) : 0);
    int jlab = (tbit ? 1 + tj : 0) * 9 + (hbit ? 1 + (hj >= 4) : 0) * 3 +
               (wbit ? 1 + (wj >= 4) : 0);
    int idxr = (ti - tj + 1) * 169 + (hi - hj + 6) * 13 + (wi - wj + 6);
    float v = rpb[idxr * 4 + head];
    if (ilab != jlab) v -= 100.f;
    if (col >= 98) v = -30000.f;
    tbl[i2] = f2bits(v);
  }
}

// =====================================================================
// win_k: one block (1024 thr, 16 waves) per window.
// LN1+shift+gather -> QKV -> attention -> proj + scatter + residual(x)
// =====================================================================
__global__ __launch_bounds__(1024) void win_k(const float* __restrict__ x,
    const float* __restrict__ n1g, const float* __restrict__ n1b,
    const bf16* __restrict__ bt_qkv, const float* __restrict__ qkv_b,
    const bf16* __restrict__ bt_proj, const float* __restrict__ proj_b,
    const unsigned short* __restrict__ tbl, float* __restrict__ out) {
  // LDS: 59136 + 34816 + 69632 = 163584 B (<= 163840)
  __shared__ __align__(16) unsigned short qk[112][264];   // Q 0..127 (later attn-out), K 128..255
  __shared__ __align__(16) unsigned short vt[128][136];   // V^T [d][k]; cols 128.. = tokmap
  __shared__ __align__(16) unsigned short pool[16 * 16 * 136]; // xn (ph1-2) / P-staging (ph3)
  auto xn = reinterpret_cast<unsigned short(*)[136]>(pool);
  auto Pl = reinterpret_cast<unsigned short(*)[16][136]>(pool);

  const int lane = threadIdx.x & 63, wave = threadIdx.x >> 6;
  const int l15 = lane & 15, lq = lane >> 4;
  const int wg = blockIdx.x;
  const int batch = wg >> 8, widx = wg & 255;
  const int tw = widx >> 6, hw = (widx >> 3) & 7, ww = widx & 7;
  const int cat = ((tw == 3) ? 4 : 0) + ((hw == 7) ? 2 : 0) + ((ww == 7) ? 1 : 0);

  // zero vt k-columns 112..127 (read by PV against P=0; must be finite)
  for (int i = threadIdx.x; i < 128 * 16; i += 1024) {
    vt[i >> 4][112 + (i & 15)] = 0;
  }

  // ---- phase 1: LN1 + shift + window gather; 7 rows per wave; tokmap on SALU
  {
    float2 gp = reinterpret_cast<const float2*>(n1g)[lane];
    float2 bp = reinterpret_cast<const float2*>(n1b)[lane];
    for (int i = 0; i < 7; i++) {
      int lrow = wave * 7 + i;
      int n = lrow > 97 ? 97 : lrow;
      int ti = n / 49, rr = n - ti * 49, hi = rr / 7, wi = rr - hi * 7;
      int t = (tw * 2 + ti + 1) & 7;
      int h = hw * 7 + hi + 3; if (h >= 56) h -= 56;
      int w = ww * 7 + wi + 3; if (w >= 56) w -= 56;
      unsigned int tok = (unsigned int)batch * THW + (t * 56 + h) * 56 + w;
      if (lane == 0) *reinterpret_cast<unsigned int*>(&vt[lrow][128]) = tok;
      const float2* src = reinterpret_cast<const float2*>(x + (size_t)tok * 128);
      float2 v = src[lane];
      float s = v.x + v.y, ss = v.x * v.x + v.y * v.y;
      #pragma unroll
      for (int m = 1; m < 64; m <<= 1) { s += __shfl_xor(s, m); ss += __shfl_xor(ss, m); }
      float mu = s * (1.f / 128.f);
      float var = ss * (1.f / 128.f) - mu * mu;
      float rs = rsqrtf(var + 1e-5f);
      float o0 = (v.x - mu) * rs * gp.x + bp.x;
      float o1 = (v.y - mu) * rs * gp.y + bp.y;
      *reinterpret_cast<unsigned int*>(&xn[lrow][lane * 2]) =
          (unsigned int)f2bits(o0) | ((unsigned int)f2bits(o1) << 16);
    }
  }
  __syncthreads();

  // ---- phase 2: QKV GEMM (112x384, K=128). 48 tasks = (ct 0..23) x (row-half)
  for (int task = wave; task < 48; task += 16) {
    const int ct = task >> 1, half = task & 1;
    const int rt0 = half ? 4 : 0, rt1 = half ? 7 : 4;
    const float bias = qkv_b[ct * 16 + l15];
    const bf16* Bp = bt_qkv + (size_t)(ct * 16 + l15) * 128 + lq * 8;
    short8 b[4];
    #pragma unroll
    for (int q = 0; q < 4; q++) b[q] = load8(Bp + q * 32);
    for (int rt = rt0; rt < rt1; rt++) {
      float4f acc = (float4f){0.f, 0.f, 0.f, 0.f};
      #pragma unroll
      for (int q = 0; q < 4; q++)
        acc = mfma16(load8u(&xn[rt * 16 + l15][q * 32 + lq * 8]), b[q], acc);
      #pragma unroll
      for (int r = 0; r < 4; r++) {
        int row = rt * 16 + lq * 4 + r;
        unsigned short hv = f2bits(acc[r] + bias);
        if (ct < 8)       qk[row][ct * 16 + l15] = hv;
        else if (ct < 16) qk[row][128 + (ct - 8) * 16 + l15] = hv;
        else              vt[(ct - 16) * 16 + l15][row] = hv;
      }
    }
  }
  __syncthreads();

  // ---- phase 3: attention. 28 tasks = (head) x (16-row block)
  for (int task = wave; task < 28; task += 16) {
    const int head = task & 3, rb = task >> 2;
    const int q0 = rb * 16;
    const unsigned short* tb = tbl + (size_t)(cat * 4 + head) * 112 * 120;

    short8 aq = load8u(&qk[q0 + l15][head * 32 + lq * 8]);
    float pv[7][4];
    #pragma unroll
    for (int t = 0; t < 7; t++) {
      short8 kb = load8u(&qk[t * 16 + l15][128 + head * 32 + lq * 8]);
      float4f s = mfma16(aq, kb, (float4f){0.f, 0.f, 0.f, 0.f});
      #pragma unroll
      for (int r = 0; r < 4; r++) {
        float bias = bits2f(tb[(q0 + lq * 4 + r) * 120 + t * 16 + l15]);
        pv[t][r] = fmaf(s[r], SCALE_QK, bias);
      }
    }

    // exact softmax over the 112-col row (cols >=98 hold -30000 -> 0)
    #pragma unroll
    for (int r = 0; r < 4; r++) {
      float m = pv[0][r];
      #pragma unroll
      for (int t = 1; t < 7; t++) m = fmaxf(m, pv[t][r]);
      #pragma unroll
      for (int d = 1; d < 16; d <<= 1) m = fmaxf(m, __shfl_xor(m, d));
      float sum = 0.f;
      #pragma unroll
      for (int t = 0; t < 7; t++) { float p = __expf(pv[t][r] - m); pv[t][r] = p; sum += p; }
      #pragma unroll
      for (int d = 1; d < 16; d <<= 1) sum += __shfl_xor(sum, d);
      float inv = 1.f / sum;
      int prow = lq * 4 + r;
      #pragma unroll
      for (int t = 0; t < 7; t++) Pl[wave][prow][t * 16 + l15] = f2bits(pv[t][r] * inv);
      Pl[wave][prow][112 + l15] = 0;   // zero cols 112..127
    }

    // O = P V
    float4f o[2];
    o[0] = (float4f){0.f, 0.f, 0.f, 0.f};
    o[1] = (float4f){0.f, 0.f, 0.f, 0.f};
    #pragma unroll
    for (int ks = 0; ks < 4; ks++) {
      short8 ap = load8u(&Pl[wave][l15][ks * 32 + lq * 8]);
      #pragma unroll
      for (int dt = 0; dt < 2; dt++) {
        short8 vb = load8u(&vt[head * 32 + dt * 16 + l15][ks * 32 + lq * 8]);
        o[dt] = mfma16(ap, vb, o[dt]);
      }
    }
    // write attn-out in place over this task's Q region
    #pragma unroll
    for (int dt = 0; dt < 2; dt++) {
      #pragma unroll
      for (int r = 0; r < 4; r++) {
        qk[q0 + lq * 4 + r][head * 32 + dt * 16 + l15] = f2bits(o[dt][r]);
      }
    }
  }
  __syncthreads();

  // ---- phase 4: proj (112x128) + scatter/unshift + residual(x) -> out
  {
    const int ct = wave & 7, half = wave >> 3;
    const int rt0 = half ? 4 : 0, rt1 = half ? 7 : 4;
    const int col = ct * 16 + l15;
    const float pb = proj_b[col];
    const bf16* Bp = bt_proj + (size_t)col * 128 + lq * 8;
    short8 b[4];
    #pragma unroll
    for (int q = 0; q < 4; q++) b[q] = load8(Bp + q * 32);
    for (int rt = rt0; rt < rt1; rt++) {
      float4f acc = (float4f){0.f, 0.f, 0.f, 0.f};
      #pragma unroll
      for (int q = 0; q < 4; q++)
        acc = mfma16(load8u(&qk[rt * 16 + l15][q * 32 + lq * 8]), b[q], acc);
      #pragma unroll
      for (int r = 0; r < 4; r++) {
        int row = rt * 16 + lq * 4 + r;
        if (row < 98) {
          unsigned int tok = *reinterpret_cast<const unsigned int*>(&vt[row][128]);
          out[(size_t)tok * 128 + col] = x[(size_t)tok * 128 + col] + acc[r] + pb;
        }
      }
    }
  }
}

// ---------------- fused LN2 + fc1 + GELU + fc2 + residual (in-place on out) --------
__global__ __launch_bounds__(256) void mlp_k(const float* xmid,
    const float* __restrict__ g, const float* __restrict__ bt,
    const bf16* __restrict__ fc1t, const float* __restrict__ fc1b,
    const bf16* __restrict__ fc2t, const float* __restrict__ fc2b,
    float* out) {
  __shared__ __align__(16) unsigned short xn[64][136];
  __shared__ __align__(16) unsigned short hid[64][136];
  const int lane = threadIdx.x & 63, wave = threadIdx.x >> 6;
  const int l15 = lane & 15, lq = lane >> 4;
  const int wm = wave & 1, wn = wave >> 1;
  const int row0 = blockIdx.x * 64;

  for (int r = 0; r < 16; r++) {
    int lrow = wave * 16 + r;
    const float2* src = reinterpret_cast<const float2*>(xmid + (size_t)(row0 + lrow) * 128);
    float2 v = src[lane];
    float s = v.x + v.y, ss = v.x * v.x + v.y * v.y;
    #pragma unroll
    for (int m = 1; m < 64; m <<= 1) { s += __shfl_xor(s, m); ss += __shfl_xor(ss, m); }
    float mu = s * (1.f / 128.f);
    float var = ss * (1.f / 128.f) - mu * mu;
    float rs = rsqrtf(var + 1e-5f);
    float2 gp = reinterpret_cast<const float2*>(g)[lane];
    float2 bp = reinterpret_cast<const float2*>(bt)[lane];
    float o0 = (v.x - mu) * rs * gp.x + bp.x;
    float o1 = (v.y - mu) * rs * gp.y + bp.y;
    *reinterpret_cast<unsigned int*>(&xn[lrow][lane * 2]) =
        (unsigned int)f2bits(o0) | ((unsigned int)f2bits(o1) << 16);
  }
  __syncthreads();

  float4f acc2[2][4];
  #pragma unroll
  for (int mt = 0; mt < 2; mt++)
    #pragma unroll
    for (int nt = 0; nt < 4; nt++) acc2[mt][nt] = (float4f){0.f, 0.f, 0.f, 0.f};

  #pragma unroll
  for (int hb = 0; hb < 4; hb++) {
    float4f acc1[2][4];
    #pragma unroll
    for (int mt = 0; mt < 2; mt++)
      #pragma unroll
      for (int nt = 0; nt < 4; nt++) acc1[mt][nt] = (float4f){0.f, 0.f, 0.f, 0.f};
    const bf16* B1 = fc1t + (size_t)(hb * 128 + wn * 64 + l15) * 128 + lq * 8;
    #pragma unroll
    for (int k0 = 0; k0 < 128; k0 += 32) {
      short8 a0 = load8u(&xn[wm * 32 + l15][k0 + lq * 8]);
      short8 a1 = load8u(&xn[wm * 32 + 16 + l15][k0 + lq * 8]);
      #pragma unroll
      for (int nt = 0; nt < 4; nt++) {
        short8 b = load8(B1 + (size_t)nt * 16 * 128 + k0);
        acc1[0][nt] = mfma16(a0, b, acc1[0][nt]);
        acc1[1][nt] = mfma16(a1, b, acc1[1][nt]);
      }
    }
    if (hb) __syncthreads();
    #pragma unroll
    for (int mt = 0; mt < 2; mt++) {
      #pragma unroll
      for (int nt = 0; nt < 4; nt++) {
        #pragma unroll
        for (int r = 0; r < 4; r++) {
          int hr = wm * 32 + mt * 16 + lq * 4 + r;
          int hc = wn * 64 + nt * 16 + l15;
          float v = acc1[mt][nt][r] + fc1b[hb * 128 + hc];
          float gl = 0.5f * v * (1.f + erff(v * 0.70710678118654752f));
          hid[hr][hc] = f2bits(gl);
        }
      }
    }
    __syncthreads();
    const bf16* B2 = fc2t + (size_t)(wn * 64 + l15) * 512 + hb * 128 + lq * 8;
    #pragma unroll
    for (int k0 = 0; k0 < 128; k0 += 32) {
      short8 a0 = load8u(&hid[wm * 32 + l15][k0 + lq * 8]);
      short8 a1 = load8u(&hid[wm * 32 + 16 + l15][k0 + lq * 8]);
      #pragma unroll
      for (int nt = 0; nt < 4; nt++) {
        short8 b = load8(B2 + (size_t)nt * 16 * 512 + k0);
        acc2[0][nt] = mfma16(a0, b, acc2[0][nt]);
        acc2[1][nt] = mfma16(a1, b, acc2[1][nt]);
      }
    }
  }

  #pragma unroll
  for (int mt = 0; mt < 2; mt++) {
    #pragma unroll
    for (int r = 0; r < 4; r++) {
      int row = row0 + wm * 32 + mt * 16 + lq * 4 + r;
      #pragma unroll
      for (int nt = 0; nt < 4; nt++) {
        int col = wn * 64 + nt * 16 + l15;
        float v = acc2[mt][nt][r] + fc2b[col];
        out[(size_t)row * 128 + col] = xmid[(size_t)row * 128 + col] + v;
      }
    }
  }
}

extern "C" void kernel_launch(void* const* d_in, const int* in_sizes, int n_in,
                              void* d_out, int out_size, void* d_ws, size_t ws_size,
                              hipStream_t stream) {
  (void)in_sizes; (void)n_in; (void)out_size; (void)ws_size;
  const float* x      = (const float*)d_in[0];
  const float* n1g    = (const float*)d_in[1];
  const float* n1b    = (const float*)d_in[2];
  const float* qkv_w  = (const float*)d_in[3];
  const float* qkv_b  = (const float*)d_in[4];
  const float* proj_w = (const float*)d_in[5];
  const float* proj_b = (const float*)d_in[6];
  const float* rpb    = (const float*)d_in[7];
  const float* n2g    = (const float*)d_in[8];
  const float* n2b    = (const float*)d_in[9];
  const float* fc1_w  = (const float*)d_in[10];
  const float* fc1_b  = (const float*)d_in[11];
  const float* fc2_w  = (const float*)d_in[12];
  const float* fc2_b  = (const float*)d_in[13];
  float* out = (float*)d_out;

  char* ws = (char*)d_ws;
  bf16* bt_qkv  = (bf16*)(ws + 0);        //  98304 B
  bf16* bt_proj = (bf16*)(ws + 98304);    //  32768 B
  bf16* bt_fc1  = (bf16*)(ws + 131072);   // 131072 B
  bf16* bt_fc2  = (bf16*)(ws + 262144);   // 131072 B
  unsigned short* tbl = (unsigned short*)(ws + 393216);  // 860160 B bias table
  // total ws ~= 1.25 MB

  // weights + bias/mask table: 196608 + 430080 = 626688 elems = 2448 blocks
  transpose_all<<<2448, 256, 0, stream>>>(qkv_w, proj_w, fc1_w, fc2_w, rpb,
                                          bt_qkv, bt_proj, bt_fc1, bt_fc2, tbl);

  // whole attention pipeline, all 8 batches, one launch; xmid lands in `out`
  win_k<<<2048, 1024, 0, stream>>>(x, n1g, n1b, bt_qkv, qkv_b, bt_proj, proj_b,
                                   tbl, out);

  // LN2 + fc1 + GELU + fc2 + residual, in place on `out`
  mlp_k<<<3136, 256, 0, stream>>>(out, n2g, n2b, bt_fc1, fc1_b, bt_fc2, fc2_b, out);
}